// Round 1
// 1681.659 us; speedup vs baseline: 1.0073x; 1.0073x over previous
//
#include <hip/hip_runtime.h>

typedef unsigned short u16;
typedef unsigned int u32;

// ---------- problem constants ----------
#define BGR 512      // graphs
#define NPG_ 64      // nodes/graph
#define MPG_ 128     // br rows/graph
#define EPG_ 200     // edges/graph (to_edge rows)
#define CN_ 256      // node channels
#define CE_ 64       // edge channels
#define NN_ (BGR*NPG_)      // 32768
#define NBR_ (BGR*MPG_)     // 65536
#define EN_ (BGR*EPG_)      // 102400
#define EBR_ (BGR*MPG_*4)   // 262144

__device__ __forceinline__ float bf2f(u16 u){ return __uint_as_float(((u32)u) << 16); }
__device__ __forceinline__ u16 f2bf(float f){
  u32 u = __float_as_uint(f);
  u32 r = u + 0x7FFFu + ((u >> 16) & 1u);   // RTNE
  return (u16)(r >> 16);
}

// ---------- zero (grid-stride) ----------
__global__ __launch_bounds__(256) void zero_k(float* __restrict__ p, size_t n){
  size_t i = (size_t)blockIdx.x*256 + threadIdx.x;
  const size_t st = (size_t)gridDim.x*256;
  for (; i < n; i += st) p[i] = 0.f;
}

// ---------- GEMM: C[M,N](bf16) = A[M,K](fp32) @ W[K,N](fp32) ----------
__global__ __launch_bounds__(256) void gemm64(const float* __restrict__ A,
                                              const float* __restrict__ W,
                                              u16* __restrict__ C,
                                              int M, int N, int K)
{
  __shared__ float sA[16][65];
  __shared__ float sB[16][65];
  const int tid = threadIdx.x;
  const int n0 = blockIdx.x * 64;
  const int m0 = blockIdx.y * 64;
  const int tx = tid & 15, ty = tid >> 4;
  const int ar = tid >> 2, ak = (tid & 3) << 2;
  const int wr = tid >> 4, wc = (tid & 15) << 2;
  float acc[4][4];
  #pragma unroll
  for (int i = 0; i < 4; i++)
    #pragma unroll
    for (int j = 0; j < 4; j++) acc[i][j] = 0.f;

  for (int k0 = 0; k0 < K; k0 += 16){
    {
      const float4 av = *(const float4*)(A + (size_t)(m0+ar)*K + k0 + ak);
      sA[ak+0][ar]=av.x; sA[ak+1][ar]=av.y; sA[ak+2][ar]=av.z; sA[ak+3][ar]=av.w;
    }
    {
      const float4 wv = *(const float4*)(W + (size_t)(k0+wr)*N + n0 + wc);
      sB[wr][wc+0]=wv.x; sB[wr][wc+1]=wv.y; sB[wr][wc+2]=wv.z; sB[wr][wc+3]=wv.w;
    }
    __syncthreads();
    #pragma unroll
    for (int kk = 0; kk < 16; kk++){
      float a0=sA[kk][ty*4+0], a1=sA[kk][ty*4+1], a2=sA[kk][ty*4+2], a3=sA[kk][ty*4+3];
      float b0=sB[kk][tx*4+0], b1=sB[kk][tx*4+1], b2=sB[kk][tx*4+2], b3=sB[kk][tx*4+3];
      acc[0][0]+=a0*b0; acc[0][1]+=a0*b1; acc[0][2]+=a0*b2; acc[0][3]+=a0*b3;
      acc[1][0]+=a1*b0; acc[1][1]+=a1*b1; acc[1][2]+=a1*b2; acc[1][3]+=a1*b3;
      acc[2][0]+=a2*b0; acc[2][1]+=a2*b1; acc[2][2]+=a2*b2; acc[2][3]+=a2*b3;
      acc[3][0]+=a3*b0; acc[3][1]+=a3*b1; acc[3][2]+=a3*b2; acc[3][3]+=a3*b3;
    }
    __syncthreads();
  }
  #pragma unroll
  for (int i = 0; i < 4; i++){
    size_t row = (size_t)(m0 + ty*4 + i)*N + n0;
    #pragma unroll
    for (int j = 0; j < 4; j++) C[row + tx*4 + j] = f2bf(acc[i][j]);
  }
}

// ---------- to_edge: fp32 -> fp32 ----------
__global__ __launch_bounds__(64) void to_edge_g(const float* __restrict__ br, float* __restrict__ eo)
{
  const int j = blockIdx.x, g = blockIdx.y, c = threadIdx.x;
  float v;
  if (j < 16) v = br[((size_t)g*128 + (j >> 1))*64 + c];
  else if (j < 80) v = (c == 0) ? 1.f : 0.f;
  else v = br[((size_t)g*128 + (j - 72))*64 + c];
  eo[((size_t)g*200 + j)*64 + c] = v;
}

// ---------- fused per-graph attention ----------
// One block per graph. 512 threads = 8 waves. Wave-per-edge; lane l covers
// channels [l*C/64, ...): C=256 -> 4 ch/lane (one uint2 = whole 512B row
// coalesced per wave), C=64 -> 1 ch/lane. Head = lane>>4; dot reduced with
// 4 shfl_xor levels inside the 16-lane head group. den + att accumulate in
// LDS (no global atomics, no f_L/f_den, no zero passes).
template<int C, int NODES, int EDGES, bool HAS_EF>
__global__ __launch_bounds__(512) void attn_graph(const u16* __restrict__ q,
                                                  const u16* __restrict__ k,
                                                  const u16* __restrict__ v,
                                                  const u16* __restrict__ ef,
                                                  const int* __restrict__ eidx, int Etot,
                                                  float scale,
                                                  float* __restrict__ att)
{
  __shared__ float s_att[NODES * C];     // N: 64KB  E: 32KB
  __shared__ float s_den[NODES * 4];
  __shared__ float s_al[EDGES * 4];
  const int tid = threadIdx.x;
  const int g = blockIdx.x;
  for (int i = tid; i < NODES * C; i += 512) s_att[i] = 0.f;
  for (int i = tid; i < NODES * 4; i += 512) s_den[i] = 0.f;
  __syncthreads();
  const int wv = tid >> 6, lane = tid & 63;
  const int h = lane >> 4;                // head of this lane's channel group
  const int e0 = g * EDGES;
  const int nbase = g * NODES;

  // ---- pass 1: logits -> exp -> LDS den ----
  for (int ee = wv; ee < EDGES; ee += 8){
    const int e = e0 + ee;
    const int s = eidx[e], d = eidx[Etot + e];
    float p;
    if (C == 256){
      const uint2 qa = *(const uint2*)(q + (size_t)d*C + lane*4);
      const uint2 ka = *(const uint2*)(k + (size_t)s*C + lane*4);
      float q0=bf2f((u16)qa.x), q1=bf2f((u16)(qa.x>>16));
      float q2=bf2f((u16)qa.y), q3=bf2f((u16)(qa.y>>16));
      float k0=bf2f((u16)ka.x), k1=bf2f((u16)(ka.x>>16));
      float k2=bf2f((u16)ka.y), k3=bf2f((u16)(ka.y>>16));
      if (HAS_EF){
        const uint2 ea = *(const uint2*)(ef + (size_t)e*C + lane*4);
        k0 += bf2f((u16)ea.x); k1 += bf2f((u16)(ea.x>>16));
        k2 += bf2f((u16)ea.y); k3 += bf2f((u16)(ea.y>>16));
      }
      p = q0*k0 + q1*k1 + q2*k2 + q3*k3;
    } else {
      float qv = bf2f(q[(size_t)d*C + lane]);
      float kv = bf2f(k[(size_t)s*C + lane]);
      if (HAS_EF) kv += bf2f(ef[(size_t)e*C + lane]);
      p = qv * kv;
    }
    p += __shfl_xor(p, 1);
    p += __shfl_xor(p, 2);
    p += __shfl_xor(p, 4);
    p += __shfl_xor(p, 8);
    if ((lane & 15) == 0){
      float lg = p * scale;
      lg = lg > 0.f ? lg : 0.2f * lg;     // leaky_relu 0.2
      const float ex = expf(lg);          // |lg| <~ 10: safe without max-sub (established)
      s_al[ee*4 + h] = ex;
      atomicAdd(&s_den[(d - nbase)*4 + h], ex);
    }
  }
  __syncthreads();

  // ---- pass 2: alpha * (v [+ ef]) -> LDS att ----
  for (int ee = wv; ee < EDGES; ee += 8){
    const int e = e0 + ee;
    const int s = eidx[e], d = eidx[Etot + e];
    const int dl = d - nbase;
    const float alpha = s_al[ee*4 + h] / (s_den[dl*4 + h] + 1e-16f);
    if (C == 256){
      const uint2 va = *(const uint2*)(v + (size_t)s*C + lane*4);
      float v0=bf2f((u16)va.x), v1=bf2f((u16)(va.x>>16));
      float v2=bf2f((u16)va.y), v3=bf2f((u16)(va.y>>16));
      if (HAS_EF){
        const uint2 ea = *(const uint2*)(ef + (size_t)e*C + lane*4);
        v0 += bf2f((u16)ea.x); v1 += bf2f((u16)(ea.x>>16));
        v2 += bf2f((u16)ea.y); v3 += bf2f((u16)(ea.y>>16));
      }
      float* dst = s_att + (size_t)dl*C + lane*4;
      atomicAdd(dst+0, alpha*v0);
      atomicAdd(dst+1, alpha*v1);
      atomicAdd(dst+2, alpha*v2);
      atomicAdd(dst+3, alpha*v3);
    } else {
      float vv = bf2f(v[(size_t)s*C + lane]);
      atomicAdd(&s_att[dl*C + lane], alpha*vv);
    }
  }
  __syncthreads();

  // ---- write out (coalesced float4) ----
  const float4* s4 = (const float4*)s_att;
  float4* a4 = (float4*)(att + (size_t)g*NODES*C);
  for (int i = tid; i < NODES*C/4; i += 512) a4[i] = s4[i];
}

// ---------- BN stats: per-channel sum & sumsq ----------
template<int C>
__global__ __launch_bounds__(256) void bn_stats_f(const float* __restrict__ a, int Nrows,
                                                  float* __restrict__ stats)
{
  const int tid = threadIdx.x;
  const int c = tid & (C - 1);
  const int sub = (C == 64) ? (tid >> 6) : 0;
  const int nsub = 256 / C;
  float s = 0.f, ss = 0.f;
  for (int r = blockIdx.x*nsub + sub; r < Nrows; r += gridDim.x*nsub){
    const float val = a[(size_t)r*C + c];
    s += val; ss += val*val;
  }
  __shared__ float rs[256], rss[256];
  rs[tid] = s; rss[tid] = ss;
  __syncthreads();
  if (tid < C){
    float S = rs[tid], SS = rss[tid];
    for (int u = 1; u < nsub; u++){ S += rs[tid + u*C]; SS += rss[tid + u*C]; }
    atomicAdd(&stats[tid], S);
    atomicAdd(&stats[C + tid], SS);
  }
}

// ---------- BN apply + ReLU + residual (all fp32) ----------
template<bool SUB>
__global__ __launch_bounds__(256) void bn_apply_f(const float* __restrict__ a,
    const float* __restrict__ stats, const float* __restrict__ gw, const float* __restrict__ bw,
    const float* __restrict__ res, float* __restrict__ o, int Nrows, int C)
{
  const size_t idx = (size_t)blockIdx.x*256 + threadIdx.x;
  const int c = (int)(idx & (size_t)(C - 1));
  const float invN = 1.0f / (float)Nrows;
  const float mu = stats[c] * invN;
  const float var = stats[C + c] * invN - mu*mu;
  const float scale = rsqrtf(var + 1e-5f) * gw[c];
  float val = (a[idx] - mu) * scale + bw[c];
  val = val > 0.f ? val : 0.f;
  const float rv = res[idx];
  o[idx] = SUB ? (rv - val) : (val + rv);
}

__global__ __launch_bounds__(256) void copy_f(const float* __restrict__ s,
                                              float* __restrict__ d, size_t n)
{
  const size_t i = (size_t)blockIdx.x*256 + threadIdx.x;
  if (i < n) d[i] = s[i];
}

__global__ __launch_bounds__(256) void super_k(const float* __restrict__ out2, float* __restrict__ sn)
{
  const int g = blockIdx.x, c = threadIdx.x;
  sn[(size_t)g*256 + c] = out2[((size_t)g*64 + 63)*256 + c];
}

// ---------- host ----------
extern "C" void kernel_launch(void* const* d_in, const int* in_sizes, int n_in,
                              void* d_out, int out_size, void* d_ws, size_t ws_size,
                              hipStream_t stream)
{
  (void)in_sizes; (void)n_in; (void)out_size; (void)ws_size;
  const float* x    = (const float*)d_in[0];
  const int*   ei   = (const int*)d_in[1];
  const float* brf  = (const float*)d_in[2];
  const int*   bei  = (const int*)d_in[3];
  const float *WqE1=(const float*)d_in[4], *WkE1=(const float*)d_in[5], *WvE1=(const float*)d_in[6];
  const float *gE1=(const float*)d_in[7],  *bE1=(const float*)d_in[8];
  const float *Wq1=(const float*)d_in[9],  *Wk1=(const float*)d_in[10], *Wv1=(const float*)d_in[11];
  const float *We1=(const float*)d_in[12];
  const float *gN1=(const float*)d_in[13], *bN1=(const float*)d_in[14];
  const float *WqE2=(const float*)d_in[15],*WkE2=(const float*)d_in[16],*WvE2=(const float*)d_in[17];
  const float *gE2=(const float*)d_in[18], *bE2=(const float*)d_in[19];
  const float *Wq2=(const float*)d_in[20], *Wk2=(const float*)d_in[21], *Wv2=(const float*)d_in[22];
  const float *We2=(const float*)d_in[23];
  const float *gN2=(const float*)d_in[24], *bN2=(const float*)d_in[25];

  // ---- workspace layout (unchanged; f_L/f_den slots now unused) ----
  char* ws = (char*)d_ws;
  u16*   h_ef    = (u16*)(ws + 0);            // 102400*256 bf16 = 52,428,800 B
  char*  p1      = ws + 52428800;             // pool: 50,331,648 B
  u16*   h_qE    = (u16*)(p1);
  u16*   h_kE    = (u16*)(p1 + 8388608);
  u16*   h_vE    = (u16*)(p1 + 16777216);
  u16*   h_qN    = (u16*)(p1);
  u16*   h_kN    = (u16*)(p1 + 16777216);
  u16*   h_vN    = (u16*)(p1 + 33554432);
  float* f_eirow = (float*)(p1);              // dead before qkv writes
  float* f_att   = (float*)(ws + 102760448);  // 33,554,432 B
  float* f_br    = (float*)(ws + 136314880);  // 16,777,216 B
  float* f_out   = (float*)(ws + 153092096);  // 33,554,432 B
  float* f_stats = (float*)(ws + 191889408);  // 8,192 B

  float* o_out2 = (float*)d_out;
  float* o_ei   = o_out2 + (size_t)NN_*CN_;
  float* o_br   = o_ei   + (size_t)EN_*CE_;
  float* o_sn   = o_br   + (size_t)NBR_*CE_;

  const int TPB = 256;
  zero_k<<<8, TPB, 0, stream>>>(f_stats, 2048);

  // ======== stage E1: conv_E -> BN -> ReLU -> add ========
  gemm64<<<dim3(1, NBR_/64), TPB, 0, stream>>>(brf, WqE1, h_qE, NBR_, CE_, CE_);
  gemm64<<<dim3(1, NBR_/64), TPB, 0, stream>>>(brf, WkE1, h_kE, NBR_, CE_, CE_);
  gemm64<<<dim3(1, NBR_/64), TPB, 0, stream>>>(brf, WvE1, h_vE, NBR_, CE_, CE_);
  attn_graph<CE_, MPG_, MPG_*4, false><<<BGR, 512, 0, stream>>>(h_qE, h_kE, h_vE, nullptr, bei, EBR_, 0.25f, f_att);
  bn_stats_f<64><<<256, TPB, 0, stream>>>(f_att, NBR_, f_stats);
  bn_apply_f<false><<<NBR_*CE_/256, TPB, 0, stream>>>(f_att, f_stats, gE1, bE1, brf, f_br, NBR_, CE_);

  // ======== stage N1 ========
  to_edge_g<<<dim3(EPG_, BGR), 64, 0, stream>>>(f_br, f_eirow);
  gemm64<<<dim3(CN_/64, EN_/64), TPB, 0, stream>>>(f_eirow, We1, h_ef, EN_, CN_, CE_);
  gemm64<<<dim3(CN_/64, NN_/64), TPB, 0, stream>>>(x, Wq1, h_qN, NN_, CN_, CN_);
  gemm64<<<dim3(CN_/64, NN_/64), TPB, 0, stream>>>(x, Wk1, h_kN, NN_, CN_, CN_);
  gemm64<<<dim3(CN_/64, NN_/64), TPB, 0, stream>>>(x, Wv1, h_vN, NN_, CN_, CN_);
  attn_graph<CN_, NPG_, EPG_, true><<<BGR, 512, 0, stream>>>(h_qN, h_kN, h_vN, h_ef, ei, EN_, 0.125f, f_att);
  bn_stats_f<256><<<256, TPB, 0, stream>>>(f_att, NN_, f_stats + 512);
  bn_apply_f<false><<<NN_*CN_/256, TPB, 0, stream>>>(f_att, f_stats + 512, gN1, bN1, x, f_out, NN_, CN_);

  // ======== stage E2 ========
  gemm64<<<dim3(1, NBR_/64), TPB, 0, stream>>>(f_br, WqE2, h_qE, NBR_, CE_, CE_);
  gemm64<<<dim3(1, NBR_/64), TPB, 0, stream>>>(f_br, WkE2, h_kE, NBR_, CE_, CE_);
  gemm64<<<dim3(1, NBR_/64), TPB, 0, stream>>>(f_br, WvE2, h_vE, NBR_, CE_, CE_);
  attn_graph<CE_, MPG_, MPG_*4, false><<<BGR, 512, 0, stream>>>(h_qE, h_kE, h_vE, nullptr, bei, EBR_, 0.25f, f_att);
  bn_stats_f<64><<<256, TPB, 0, stream>>>(f_att, NBR_, f_stats + 1024);
  bn_apply_f<true><<<NBR_*CE_/256, TPB, 0, stream>>>(f_att, f_stats + 1024, gE2, bE2, f_br, f_br, NBR_, CE_);

  // outputs: br = br2, ei = to_edge(br2)
  copy_f<<<NBR_*CE_/256, TPB, 0, stream>>>(f_br, o_br, (size_t)NBR_*CE_);
  to_edge_g<<<dim3(EPG_, BGR), 64, 0, stream>>>(f_br, o_ei);

  // ======== stage N2 ========
  gemm64<<<dim3(CN_/64, EN_/64), TPB, 0, stream>>>(o_ei, We2, h_ef, EN_, CN_, CE_);
  gemm64<<<dim3(CN_/64, NN_/64), TPB, 0, stream>>>(f_out, Wq2, h_qN, NN_, CN_, CN_);
  gemm64<<<dim3(CN_/64, NN_/64), TPB, 0, stream>>>(f_out, Wk2, h_kN, NN_, CN_, CN_);
  gemm64<<<dim3(CN_/64, NN_/64), TPB, 0, stream>>>(f_out, Wv2, h_vN, NN_, CN_, CN_);
  attn_graph<CN_, NPG_, EPG_, true><<<BGR, 512, 0, stream>>>(h_qN, h_kN, h_vN, h_ef, ei, EN_, 0.125f, f_att);
  bn_stats_f<256><<<256, TPB, 0, stream>>>(f_att, NN_, f_stats + 1536);
  bn_apply_f<true><<<NN_*CN_/256, TPB, 0, stream>>>(f_att, f_stats + 1536, gN2, bN2, f_out, o_out2, NN_, CN_);

  super_k<<<BGR, TPB, 0, stream>>>(o_out2, o_sn);
}